// Round 7
// baseline (87.745 us; speedup 1.0000x reference)
//
#include <hip/hip_runtime.h>
#include <hip/hip_fp16.h>

constexpr int Bn = 2, C = 21, H = 256, W = 256, HW = H * W;
constexpr int K = 5, K2 = 25;
constexpr int TW = 32, TH = 8;            // 256 pixels per block
constexpr int LH = TH + 4, LW = TW + 4;   // 12 x 36 staged tile
constexpr int NCELL = LH * LW;            // 432
constexpr int CQ = 6;                     // channel quads (C padded to 24)
constexpr int NCH0 = 12;                  // half0 owns c0..11 (quads 0-2)
constexpr int NCH1 = 9;                   // half1 owns c12..20 (quads 3-5)

// ---------------------------------------------------------------------------
// Prep: bilateral weights (fp16) + logits converted to fp16.
// w[b][k][p] = spatial_w[k] * color_w(b,k,p).
// ---------------------------------------------------------------------------
__global__ __launch_bounds__(256) void prep_kernel(
        const float* __restrict__ img, const float* __restrict__ logits,
        __half* __restrict__ w16, __half* __restrict__ lg16) {
    int idx = blockIdx.x * 256 + threadIdx.x;
    if (idx >= Bn * HW) return;
    int b = idx / HW, p = idx % HW;
    int y = p / W, x = p % W;
    const float* im = img + (size_t)b * 3 * HW;
    float c0 = im[p], c1 = im[HW + p], c2 = im[2 * HW + p];
    float S = 0.f;
#pragma unroll
    for (int k = 0; k < K2; ++k) {
        int dy = k / K - 2, dx = k % K - 2;
        S += __expf(-(float)(dy * dy + dx * dx) * 0.02f);   // sigma_s = 5
    }
    float invS = 1.f / S;
#pragma unroll
    for (int k = 0; k < K2; ++k) {
        int dy = k / K - 2, dx = k % K - 2;
        int ny = y + dy, nx = x + dx;
        float d0 = -c0, d1 = -c1, d2 = -c2;                 // zero-padded nbr
        if ((unsigned)ny < H && (unsigned)nx < W) {
            int np = ny * W + nx;
            d0 += im[np]; d1 += im[HW + np]; d2 += im[2 * HW + np];
        }
        float sk = __expf(-(float)(dy * dy + dx * dx) * 0.02f);
        float cw = __expf(-(d0 * d0 + d1 * d1 + d2 * d2) * 50.f);  // sigma_c=0.1
        w16[((size_t)b * K2 + k) * HW + p] = __float2half(sk * invS * cw);
    }
    // logits -> fp16 copy (used by all iterations)
    const float* lg = logits + (size_t)b * C * HW + p;
    __half* lo = lg16 + (size_t)b * C * HW + p;
#pragma unroll
    for (int c = 0; c < C; ++c)
        lo[(size_t)c * HW] = __float2half(lg[(size_t)c * HW]);
}

// ---------------------------------------------------------------------------
// One mean-field iteration. 512 threads = 2 threads/pixel. Identical
// structure to R6 (proven); all global q/w/logits traffic is fp16.
// LDS stays f32 quad-float4; taps are 3x ds_read_b128, conflict-free.
// Spatial gaussian (sigma=0.1) is a delta => wk[12] += 1.
// compat == -I fast path (runtime-verified, block-uniform).
// init!=0: staging computes q0 = softmax(logits) per cell.
// final!=0: write f32 to outf, else fp16 to qout16.
// ---------------------------------------------------------------------------
__global__ __launch_bounds__(512, 4) void crf_iter(
        const __half* __restrict__ qin16, const __half* __restrict__ w16,
        const __half* __restrict__ lg16, const float* __restrict__ compat,
        __half* __restrict__ qout16, float* __restrict__ outf,
        int init, int final_) {
    __shared__ float4 sq4[CQ][LH][LW];   // 41472 B (also m-exchange, slow path)
    __shared__ float scm[C * C];         // 1764 B

    const int b = blockIdx.z;
    const int x0 = blockIdx.x * TW, y0 = blockIdx.y * TH;
    const int tid = threadIdx.x;
    const int px = tid & 31;
    const int half = (tid >> 5) & 1;
    const int py = tid >> 6;
    const int x = x0 + px, y = y0 + py, p = y * W + x;
    const int pi = py * TW + px;
    const int qoff = half * 3;
    const int cbase = half ? NCH0 : 0;
    const int nch = half ? NCH1 : NCH0;

    // ---- stage compat (+ -I check) ----
    int ok = 1;
    for (int i = tid; i < C * C; i += 512) {
        float v = compat[i];
        scm[i] = v;
        ok &= (v == ((i / C == i % C) ? -1.0f : 0.0f));
    }

    float* sqf = (float*)&sq4[0][0][0];

    // ---- stage q tile (2-halo) in quad-interleaved f32 layout ----
    if (init) {
        if (tid < NCELL) {
            int ly = tid / LW, lx = tid % LW;
            int gy = y0 + ly - 2, gx = x0 + lx - 2;
            float vals[24];
            if ((unsigned)gy < H && (unsigned)gx < W) {
                const __half* lg = lg16 + (size_t)b * C * HW + gy * W + gx;
                float zz[C], mx = -1e30f;
#pragma unroll
                for (int c = 0; c < C; ++c) {
                    zz[c] = __half2float(lg[(size_t)c * HW]);
                    mx = fmaxf(mx, zz[c]);
                }
                float s = 0.f;
#pragma unroll
                for (int c = 0; c < C; ++c) { zz[c] = __expf(zz[c] - mx); s += zz[c]; }
                float inv = 1.f / s;
#pragma unroll
                for (int c = 0; c < 24; ++c) vals[c] = (c < C) ? zz[c] * inv : 0.f;
            } else {
#pragma unroll
                for (int c = 0; c < 24; ++c) vals[c] = 0.f;
            }
#pragma unroll
            for (int c = 0; c < 24; ++c)
                sqf[((c >> 2) * NCELL + tid) * 4 + (c & 3)] = vals[c];
        }
    } else {
        const __half* qsrc = qin16 + (size_t)b * C * HW;
        for (int i = tid; i < CQ * NCELL; i += 512) {
            int g = i / NCELL, r = i % NCELL;
            int ly = r / LW, lx = r % LW;
            int gy = y0 + ly - 2, gx = x0 + lx - 2;
            float4 v = make_float4(0.f, 0.f, 0.f, 0.f);
            if ((unsigned)gy < H && (unsigned)gx < W) {
                const __half* qp = qsrc + gy * W + gx;
                int c0 = 4 * g;
                v.x = __half2float(qp[(size_t)c0 * HW]);
                v.y = (c0 + 1 < C) ? __half2float(qp[(size_t)(c0 + 1) * HW]) : 0.f;
                v.z = (c0 + 2 < C) ? __half2float(qp[(size_t)(c0 + 2) * HW]) : 0.f;
                v.w = (c0 + 3 < C) ? __half2float(qp[(size_t)(c0 + 3) * HW]) : 0.f;
            }
            sq4[g][ly][lx] = v;
        }
    }

    // ---- per-pixel loads (issued before the barrier, in flight across it) --
    float wk[K2];
#pragma unroll
    for (int k = 0; k < K2; ++k)
        wk[k] = __half2float(w16[((size_t)b * K2 + k) * HW + p]);
    wk[12] += 1.0f;                     // fold identity (delta) spatial conv
    const __half* lgp = lg16 + (size_t)b * C * HW + p;
    float lgv[NCH0];
#pragma unroll
    for (int cc = 0; cc < NCH0; ++cc)
        lgv[cc] = (cc < nch) ? __half2float(lgp[(size_t)(cbase + cc) * HW]) : 0.f;

    const int fast = __syncthreads_and(ok);

    // ---- bilateral message passing: 25 taps x 3 quad reads ----
    float mreg[NCH0];
#pragma unroll
    for (int i = 0; i < NCH0; ++i) mreg[i] = 0.f;
#pragma unroll
    for (int k = 0; k < K2; ++k) {
        const int ly = py + k / K, lx = px + k % K;
        const float wv = wk[k];
#pragma unroll
        for (int g = 0; g < 3; ++g) {
            float4 t = sq4[qoff + g][ly][lx];
            mreg[4 * g + 0] += wv * t.x;
            mreg[4 * g + 1] += wv * t.y;
            mreg[4 * g + 2] += wv * t.z;
            mreg[4 * g + 3] += wv * t.w;
        }
    }

    // ---- compatibility transform ----
    float z[NCH0];
    if (fast) {                          // compat == -I: z = logits + m
#pragma unroll
        for (int cc = 0; cc < NCH0; ++cc) z[cc] = lgv[cc] + mreg[cc];
    } else {                             // general matvec; reuse sq4 as exchange
        __syncthreads();                 // all tap reads done
        float* smf = sqf;                // [256][C] region (21.5 KB < 41 KB)
#pragma unroll
        for (int cc = 0; cc < NCH0; ++cc)
            if (cc < nch) smf[pi * C + cbase + cc] = mreg[cc];
        __syncthreads();
        float mall[C];
#pragma unroll
        for (int j = 0; j < C; ++j) mall[j] = smf[pi * C + j];
#pragma unroll
        for (int cc = 0; cc < NCH0; ++cc) {
            float pw = 0.f;
#pragma unroll
            for (int j = 0; j < C; ++j) pw += scm[(cbase + cc) * C + j] * mall[j];
            z[cc] = lgv[cc] - pw;
        }
    }

    // ---- softmax across the two channel-halves (lane l <-> l+32) ----
    float mx = -1e30f;
#pragma unroll
    for (int cc = 0; cc < NCH0; ++cc) if (cc < nch) mx = fmaxf(mx, z[cc]);
    mx = fmaxf(mx, __shfl_xor(mx, 32));
    float s = 0.f;
#pragma unroll
    for (int cc = 0; cc < NCH0; ++cc)
        if (cc < nch) { z[cc] = __expf(z[cc] - mx); s += z[cc]; }
    s += __shfl_xor(s, 32);
    float inv = 1.f / s;

    if (final_) {
        float* qo = outf + (size_t)b * C * HW + p;
#pragma unroll
        for (int cc = 0; cc < NCH0; ++cc)
            if (cc < nch) qo[(size_t)(cbase + cc) * HW] = z[cc] * inv;
    } else {
        __half* qo = qout16 + (size_t)b * C * HW + p;
#pragma unroll
        for (int cc = 0; cc < NCH0; ++cc)
            if (cc < nch) qo[(size_t)(cbase + cc) * HW] = __float2half(z[cc] * inv);
    }
}

// ---------------------------------------------------------------------------
extern "C" void kernel_launch(void* const* d_in, const int* in_sizes, int n_in,
                              void* d_out, int out_size, void* d_ws, size_t ws_size,
                              hipStream_t stream) {
    const float* logits = (const float*)d_in[0];
    const float* img    = (const float*)d_in[1];
    // d_in[2] = gt_edges (dead code in reference)
    const float* compat = (const float*)d_in[3];
    float* out = (float*)d_out;

    __half* qa16 = (__half*)d_ws;                       // Bn*C*HW halfs
    __half* qb16 = qa16 + (size_t)Bn * C * HW;          // Bn*C*HW halfs
    __half* w16  = qb16 + (size_t)Bn * C * HW;          // Bn*K2*HW halfs
    __half* lg16 = w16 + (size_t)Bn * K2 * HW;          // Bn*C*HW halfs

    int nb = (Bn * HW + 255) / 256;
    prep_kernel<<<nb, 256, 0, stream>>>(img, logits, w16, lg16);

    dim3 g(W / TW, H / TH, Bn);                         // 8 x 32 x 2 = 512 blocks
    crf_iter<<<g, 512, 0, stream>>>(qa16, w16, lg16, compat, qb16, out, 1, 0);
    crf_iter<<<g, 512, 0, stream>>>(qb16, w16, lg16, compat, qa16, out, 0, 0);
    crf_iter<<<g, 512, 0, stream>>>(qa16, w16, lg16, compat, qb16, out, 0, 0);
    crf_iter<<<g, 512, 0, stream>>>(qb16, w16, lg16, compat, qa16, out, 0, 0);
    crf_iter<<<g, 512, 0, stream>>>(qa16, w16, lg16, compat, qb16, out, 0, 1);
}

// Round 8
// 85.284 us; speedup vs baseline: 1.0289x; 1.0289x over previous
//
#include <hip/hip_runtime.h>

constexpr int Bn = 2, C = 21, H = 256, W = 256, HW = H * W;
constexpr int K = 5, K2 = 25;
constexpr int TW = 32, TH = 4;            // 128 pixels per block
constexpr int LH = TH + 4, LW = TW + 4;   // 8 x 36 staged tile
constexpr int NCELL = LH * LW;            // 288
constexpr int CQ = 6;                     // channel quads (C padded to 24)
constexpr int NCH0 = 12;                  // half0 owns c0..11 (quads 0-2)
constexpr int NCH1 = 9;                   // half1 owns c12..20 (quads 3-5)
constexpr int NT = 256;                   // threads per block (2 per pixel)

// ---------------------------------------------------------------------------
// Prep: bilateral weights. w[b][k][p] = spatial_w[k] * color_w(b,k,p).
// ---------------------------------------------------------------------------
__global__ __launch_bounds__(256) void prep_kernel(
        const float* __restrict__ img, float* __restrict__ w) {
    int idx = blockIdx.x * 256 + threadIdx.x;
    if (idx >= Bn * HW) return;
    int b = idx / HW, p = idx % HW;
    int y = p / W, x = p % W;
    const float* im = img + (size_t)b * 3 * HW;
    float c0 = im[p], c1 = im[HW + p], c2 = im[2 * HW + p];
    float S = 0.f;
#pragma unroll
    for (int k = 0; k < K2; ++k) {
        int dy = k / K - 2, dx = k % K - 2;
        S += __expf(-(float)(dy * dy + dx * dx) * 0.02f);   // sigma_s = 5
    }
    float invS = 1.f / S;
#pragma unroll
    for (int k = 0; k < K2; ++k) {
        int dy = k / K - 2, dx = k % K - 2;
        int ny = y + dy, nx = x + dx;
        float d0 = -c0, d1 = -c1, d2 = -c2;                 // zero-padded nbr
        if ((unsigned)ny < H && (unsigned)nx < W) {
            int np = ny * W + nx;
            d0 += im[np]; d1 += im[HW + np]; d2 += im[2 * HW + np];
        }
        float sk = __expf(-(float)(dy * dy + dx * dx) * 0.02f);
        float cw = __expf(-(d0 * d0 + d1 * d1 + d2 * d2) * 50.f);  // sigma_c=0.1
        w[((size_t)b * K2 + k) * HW + p] = sk * invS * cw;
    }
}

// ---------------------------------------------------------------------------
// One mean-field iteration. 256 threads = 2 threads/pixel on a 32x4 tile;
// 1024 blocks = 4 independent blocks/CU (cross-block stage/compute overlap).
// LDS: channel-quad float4 tiles; taps = 3x ds_read_b128, conflict-free.
// Spatial gaussian (sigma=0.1) is a delta => wk[12] += 1.
// compat == -I fast path (runtime-verified, block-uniform).
// init!=0: staging computes q0 = softmax(logits) per cell.
// ---------------------------------------------------------------------------
__global__ __launch_bounds__(NT, 4) void crf_iter(
        const float* __restrict__ qin, const float* __restrict__ w,
        const float* __restrict__ logits, const float* __restrict__ compat,
        float* __restrict__ qout, int init) {
    __shared__ float4 sq4[CQ][LH][LW];   // 27648 B (also m-exchange, slow path)
    __shared__ float scm[C * C];         // 1764 B

    const int b = blockIdx.z;
    const int x0 = blockIdx.x * TW, y0 = blockIdx.y * TH;
    const int tid = threadIdx.x;
    const int px = tid & 31;
    const int half = (tid >> 5) & 1;
    const int py = tid >> 6;             // 0..3
    const int x = x0 + px, y = y0 + py, p = y * W + x;
    const int pi = py * TW + px;         // 0..127
    const int qoff = half * 3;
    const int cbase = half ? NCH0 : 0;
    const int nch = half ? NCH1 : NCH0;

    // ---- stage compat (+ -I check) ----
    int ok = 1;
    for (int i = tid; i < C * C; i += NT) {
        float v = compat[i];
        scm[i] = v;
        ok &= (v == ((i / C == i % C) ? -1.0f : 0.0f));
    }

    float* sqf = (float*)&sq4[0][0][0];

    // ---- stage q tile (2-halo) in quad-interleaved f32 layout ----
    if (init) {
        for (int cell = tid; cell < NCELL; cell += NT) {
            int ly = cell / LW, lx = cell % LW;
            int gy = y0 + ly - 2, gx = x0 + lx - 2;
            float vals[24];
            if ((unsigned)gy < H && (unsigned)gx < W) {
                const float* lg = logits + (size_t)b * C * HW + gy * W + gx;
                float zz[C], mx = -1e30f;
#pragma unroll
                for (int c = 0; c < C; ++c) {
                    zz[c] = lg[(size_t)c * HW];
                    mx = fmaxf(mx, zz[c]);
                }
                float s = 0.f;
#pragma unroll
                for (int c = 0; c < C; ++c) { zz[c] = __expf(zz[c] - mx); s += zz[c]; }
                float inv = 1.f / s;
#pragma unroll
                for (int c = 0; c < 24; ++c) vals[c] = (c < C) ? zz[c] * inv : 0.f;
            } else {
#pragma unroll
                for (int c = 0; c < 24; ++c) vals[c] = 0.f;
            }
#pragma unroll
            for (int c = 0; c < 24; ++c)
                sqf[((c >> 2) * NCELL + cell) * 4 + (c & 3)] = vals[c];
        }
    } else {
        const float* qsrc = qin + (size_t)b * C * HW;
#pragma unroll
        for (int t = 0; t < 7; ++t) {               // 6*288/256 = 6.75 trips
            int i = t * NT + tid;
            if (i < CQ * NCELL) {
                int g = i / NCELL, r = i % NCELL;
                int ly = r / LW, lx = r % LW;
                int gy = y0 + ly - 2, gx = x0 + lx - 2;
                float4 v = make_float4(0.f, 0.f, 0.f, 0.f);
                if ((unsigned)gy < H && (unsigned)gx < W) {
                    const float* qp = qsrc + gy * W + gx;
                    int c0 = 4 * g;
                    v.x = qp[(size_t)c0 * HW];
                    v.y = (c0 + 1 < C) ? qp[(size_t)(c0 + 1) * HW] : 0.f;
                    v.z = (c0 + 2 < C) ? qp[(size_t)(c0 + 2) * HW] : 0.f;
                    v.w = (c0 + 3 < C) ? qp[(size_t)(c0 + 3) * HW] : 0.f;
                }
                sq4[g][ly][lx] = v;
            }
        }
    }

    // ---- per-pixel loads (issued before the barrier, in flight across it) --
    float wk[K2];
#pragma unroll
    for (int k = 0; k < K2; ++k) wk[k] = w[((size_t)b * K2 + k) * HW + p];
    wk[12] += 1.0f;                     // fold identity (delta) spatial conv
    const float* lgp = logits + (size_t)b * C * HW + p;
    float lgv[NCH0];
#pragma unroll
    for (int cc = 0; cc < NCH0; ++cc)
        lgv[cc] = (cc < nch) ? lgp[(size_t)(cbase + cc) * HW] : 0.f;

    const int fast = __syncthreads_and(ok);

    // ---- bilateral message passing: 25 taps x 3 quad reads ----
    float mreg[NCH0];
#pragma unroll
    for (int i = 0; i < NCH0; ++i) mreg[i] = 0.f;
#pragma unroll
    for (int k = 0; k < K2; ++k) {
        const int ly = py + k / K, lx = px + k % K;
        const float wv = wk[k];
#pragma unroll
        for (int g = 0; g < 3; ++g) {
            float4 t = sq4[qoff + g][ly][lx];
            mreg[4 * g + 0] += wv * t.x;
            mreg[4 * g + 1] += wv * t.y;
            mreg[4 * g + 2] += wv * t.z;
            mreg[4 * g + 3] += wv * t.w;
        }
    }

    // ---- compatibility transform ----
    float z[NCH0];
    if (fast) {                          // compat == -I: z = logits + m
#pragma unroll
        for (int cc = 0; cc < NCH0; ++cc) z[cc] = lgv[cc] + mreg[cc];
    } else {                             // general matvec; reuse sq4 as exchange
        __syncthreads();                 // all tap reads done
        float* smf = sqf;                // [128][C] region (10.7 KB < 27.6 KB)
#pragma unroll
        for (int cc = 0; cc < NCH0; ++cc)
            if (cc < nch) smf[pi * C + cbase + cc] = mreg[cc];
        __syncthreads();
        float mall[C];
#pragma unroll
        for (int j = 0; j < C; ++j) mall[j] = smf[pi * C + j];
#pragma unroll
        for (int cc = 0; cc < NCH0; ++cc) {
            float pw = 0.f;
#pragma unroll
            for (int j = 0; j < C; ++j) pw += scm[(cbase + cc) * C + j] * mall[j];
            z[cc] = lgv[cc] - pw;
        }
    }

    // ---- softmax across the two channel-halves (lane l <-> l+32) ----
    float mx = -1e30f;
#pragma unroll
    for (int cc = 0; cc < NCH0; ++cc) if (cc < nch) mx = fmaxf(mx, z[cc]);
    mx = fmaxf(mx, __shfl_xor(mx, 32));
    float s = 0.f;
#pragma unroll
    for (int cc = 0; cc < NCH0; ++cc)
        if (cc < nch) { z[cc] = __expf(z[cc] - mx); s += z[cc]; }
    s += __shfl_xor(s, 32);
    float inv = 1.f / s;
    float* qo = qout + (size_t)b * C * HW + p;
#pragma unroll
    for (int cc = 0; cc < NCH0; ++cc)
        if (cc < nch) qo[(size_t)(cbase + cc) * HW] = z[cc] * inv;
}

// ---------------------------------------------------------------------------
extern "C" void kernel_launch(void* const* d_in, const int* in_sizes, int n_in,
                              void* d_out, int out_size, void* d_ws, size_t ws_size,
                              hipStream_t stream) {
    const float* logits = (const float*)d_in[0];
    const float* img    = (const float*)d_in[1];
    // d_in[2] = gt_edges (dead code in reference)
    const float* compat = (const float*)d_in[3];
    float* out = (float*)d_out;

    float* qa   = (float*)d_ws;                     // Bn*C*HW floats
    float* qb   = qa + (size_t)Bn * C * HW;         // Bn*C*HW floats
    float* wbuf = qb + (size_t)Bn * C * HW;         // Bn*K2*HW floats

    int nb = (Bn * HW + 255) / 256;
    prep_kernel<<<nb, 256, 0, stream>>>(img, wbuf);

    dim3 g(W / TW, H / TH, Bn);                     // 8 x 64 x 2 = 1024 blocks
    crf_iter<<<g, NT, 0, stream>>>(qa, wbuf, logits, compat, qb, 1);  // q0 inline
    crf_iter<<<g, NT, 0, stream>>>(qb, wbuf, logits, compat, qa, 0);
    crf_iter<<<g, NT, 0, stream>>>(qa, wbuf, logits, compat, qb, 0);
    crf_iter<<<g, NT, 0, stream>>>(qb, wbuf, logits, compat, qa, 0);
    crf_iter<<<g, NT, 0, stream>>>(qa, wbuf, logits, compat, out, 0);
}

// Round 9
// 73.534 us; speedup vs baseline: 1.1933x; 1.1598x over previous
//
#include <hip/hip_runtime.h>
#include <hip/hip_fp16.h>

constexpr int Bn = 2, C = 21, H = 256, W = 256, HW = H * W;
constexpr int K = 5, K2 = 25;
constexpr int TW = 32, TH = 4;            // 128 pixels per block
constexpr int LH = TH + 4, LW = TW + 4;   // 8 x 36 staged tile
constexpr int NCELL = LH * LW;            // 288
constexpr int CQ = 6;                     // channel quads (C padded to 24)
constexpr int NCH0 = 12;                  // half0 owns c0..11 (quads 0-2)
constexpr int NCH1 = 9;                   // half1 owns c12..20 (quads 3-5)
constexpr int NT = 256;                   // threads per block (2 per pixel)

union H2U { __half2 h; unsigned int u; };

// ---------------------------------------------------------------------------
// One mean-field iteration; 5 launches total (prep folded into init pass).
// 256 threads = 2 threads/pixel on a 32x4 tile; 1024 blocks = 4 blocks/CU.
// LDS q tile is fp16-packed: quad cell = 2 x __half2 (8 B) -> taps are
// 3x ds_read_b64 + 6x v_pk_fma_f16 (half the LDS bytes of the f32 layout).
// fp16 accumulation split into two ~13-tap partials, combined in f32.
// w is packed half2 in wbuf with the center identity (+1) pre-folded.
// compat == -I fast path (runtime-verified); spatial gaussian is a delta.
// init!=0: stage q0 = softmax(logits) per cell AND compute w from an img
// tile (writing wbuf for the later iterations).
// ---------------------------------------------------------------------------
__global__ __launch_bounds__(NT, 4) void crf_iter(
        const float* __restrict__ qin, unsigned int* __restrict__ wbuf,
        const float* __restrict__ logits, const float* __restrict__ img,
        const float* __restrict__ compat, float* __restrict__ qout, int init) {
    __shared__ __align__(16) __half2 sqh[CQ][LH][LW][2];  // 13824 B
    __shared__ float4 simg[NCELL];                        // 4608 B (init only)
    __shared__ float scm[C * C];                          // 1764 B

    const int b = blockIdx.z;
    const int x0 = blockIdx.x * TW, y0 = blockIdx.y * TH;
    const int tid = threadIdx.x;
    const int px = tid & 31;
    const int half = (tid >> 5) & 1;
    const int py = tid >> 6;             // 0..3
    const int x = x0 + px, y = y0 + py, p = y * W + x;
    const int pi = py * TW + px;         // 0..127
    const int qoff = half * 3;
    const int cbase = half ? NCH0 : 0;
    const int nch = half ? NCH1 : NCH0;

    // ---- stage compat (+ -I check) ----
    int ok = 1;
    for (int i = tid; i < C * C; i += NT) {
        float v = compat[i];
        scm[i] = v;
        ok &= (v == ((i / C == i % C) ? -1.0f : 0.0f));
    }

    // ---- stage q tile (2-halo) as packed half2 quads ----
    if (init) {
        const float* im = img + (size_t)b * 3 * HW;
        for (int cell = tid; cell < NCELL; cell += NT) {
            int ly = cell / LW, lx = cell % LW;
            int gy = y0 + ly - 2, gx = x0 + lx - 2;
            float4 iv = make_float4(0.f, 0.f, 0.f, 0.f);
            float vals[24];
            if ((unsigned)gy < H && (unsigned)gx < W) {
                int np = gy * W + gx;
                iv.x = im[np]; iv.y = im[HW + np]; iv.z = im[2 * HW + np];
                const float* lg = logits + (size_t)b * C * HW + np;
                float zz[C], mx = -1e30f;
#pragma unroll
                for (int c = 0; c < C; ++c) {
                    zz[c] = lg[(size_t)c * HW];
                    mx = fmaxf(mx, zz[c]);
                }
                float s = 0.f;
#pragma unroll
                for (int c = 0; c < C; ++c) { zz[c] = __expf(zz[c] - mx); s += zz[c]; }
                float inv = 1.f / s;
#pragma unroll
                for (int c = 0; c < 24; ++c) vals[c] = (c < C) ? zz[c] * inv : 0.f;
            } else {
#pragma unroll
                for (int c = 0; c < 24; ++c) vals[c] = 0.f;
            }
            simg[cell] = iv;
#pragma unroll
            for (int g = 0; g < CQ; ++g) {
                sqh[g][ly][lx][0] = __floats2half2_rn(vals[4 * g + 0], vals[4 * g + 1]);
                sqh[g][ly][lx][1] = __floats2half2_rn(vals[4 * g + 2], vals[4 * g + 3]);
            }
        }
    } else {
        const float* qsrc = qin + (size_t)b * C * HW;
        for (int i = tid; i < CQ * NCELL; i += NT) {
            int g = i / NCELL, r = i % NCELL;
            int ly = r / LW, lx = r % LW;
            int gy = y0 + ly - 2, gx = x0 + lx - 2;
            float4 v = make_float4(0.f, 0.f, 0.f, 0.f);
            if ((unsigned)gy < H && (unsigned)gx < W) {
                const float* qp = qsrc + gy * W + gx;
                int c0 = 4 * g;
                v.x = qp[(size_t)c0 * HW];
                v.y = (c0 + 1 < C) ? qp[(size_t)(c0 + 1) * HW] : 0.f;
                v.z = (c0 + 2 < C) ? qp[(size_t)(c0 + 2) * HW] : 0.f;
                v.w = (c0 + 3 < C) ? qp[(size_t)(c0 + 3) * HW] : 0.f;
            }
            sqh[g][ly][lx][0] = __floats2half2_rn(v.x, v.y);
            sqh[g][ly][lx][1] = __floats2half2_rn(v.z, v.w);
        }
    }

    // ---- per-pixel loads that don't need LDS (issued before the barrier) ---
    __half2 wk2[K2];
    if (!init) {
#pragma unroll
        for (int k = 0; k < K2; ++k) {
            H2U cv; cv.u = wbuf[((size_t)b * K2 + k) * HW + p];
            wk2[k] = cv.h;
        }
    }
    const float* lgp = logits + (size_t)b * C * HW + p;
    float lgv[NCH0];
#pragma unroll
    for (int cc = 0; cc < NCH0; ++cc)
        lgv[cc] = (cc < nch) ? lgp[(size_t)(cbase + cc) * HW] : 0.f;

    const int fast = __syncthreads_and(ok);

    // ---- init: compute bilateral weights from the staged img tile ----------
    if (init) {
        float4 ctr = simg[(py + 2) * LW + (px + 2)];
        float S = 0.f;
#pragma unroll
        for (int k = 0; k < K2; ++k) {
            int dy = k / K - 2, dx = k % K - 2;
            S += __expf(-(float)(dy * dy + dx * dx) * 0.02f);   // sigma_s = 5
        }
        float invS = 1.f / S;
#pragma unroll
        for (int k = 0; k < K2; ++k) {
            int dy = k / K - 2, dx = k % K - 2;
            float4 nb = simg[(py + 2 + dy) * LW + (px + 2 + dx)];
            float d0 = nb.x - ctr.x, d1 = nb.y - ctr.y, d2 = nb.z - ctr.z;
            float sk = __expf(-(float)(dy * dy + dx * dx) * 0.02f);
            float wv = sk * invS * __expf(-(d0 * d0 + d1 * d1 + d2 * d2) * 50.f);
            if (k == 12) wv += 1.0f;        // fold identity (delta) spatial conv
            H2U cv; cv.h = __float2half2_rn(wv);
            wk2[k] = cv.h;
            wbuf[((size_t)b * K2 + k) * HW + p] = cv.u;   // for iters 1..4
        }
    }

    // ---- bilateral message passing: 25 taps x 3 ds_read_b64, pk_fma_f16 ---
    const __half2 zero2 = __float2half2_rn(0.f);
    __half2 a01A[3], a23A[3], a01B[3], a23B[3];
#pragma unroll
    for (int g = 0; g < 3; ++g) { a01A[g] = zero2; a23A[g] = zero2;
                                  a01B[g] = zero2; a23B[g] = zero2; }
#pragma unroll
    for (int k = 0; k < K2; ++k) {
        const int ly = py + k / K, lx = px + k % K;
        const __half2 wv = wk2[k];
#pragma unroll
        for (int g = 0; g < 3; ++g) {
            const uint2 raw = *reinterpret_cast<const uint2*>(&sqh[qoff + g][ly][lx][0]);
            H2U q01, q23; q01.u = raw.x; q23.u = raw.y;
            if (k < 13) {
                a01A[g] = __hfma2(wv, q01.h, a01A[g]);
                a23A[g] = __hfma2(wv, q23.h, a23A[g]);
            } else {
                a01B[g] = __hfma2(wv, q01.h, a01B[g]);
                a23B[g] = __hfma2(wv, q23.h, a23B[g]);
            }
        }
    }
    float mreg[NCH0];
#pragma unroll
    for (int g = 0; g < 3; ++g) {
        float2 lA = __half22float2(a01A[g]), lB = __half22float2(a01B[g]);
        float2 hA = __half22float2(a23A[g]), hB = __half22float2(a23B[g]);
        mreg[4 * g + 0] = lA.x + lB.x;
        mreg[4 * g + 1] = lA.y + lB.y;
        mreg[4 * g + 2] = hA.x + hB.x;
        mreg[4 * g + 3] = hA.y + hB.y;
    }

    // ---- compatibility transform ----
    float z[NCH0];
    if (fast) {                          // compat == -I: z = logits + m
#pragma unroll
        for (int cc = 0; cc < NCH0; ++cc) z[cc] = lgv[cc] + mreg[cc];
    } else {                             // general matvec; reuse sqh as exchange
        __syncthreads();                 // all tap reads done
        float* smf = (float*)&sqh[0][0][0][0];   // 128*21*4 = 10752 B < 13824
#pragma unroll
        for (int cc = 0; cc < NCH0; ++cc)
            if (cc < nch) smf[pi * C + cbase + cc] = mreg[cc];
        __syncthreads();
        float mall[C];
#pragma unroll
        for (int j = 0; j < C; ++j) mall[j] = smf[pi * C + j];
#pragma unroll
        for (int cc = 0; cc < NCH0; ++cc) {
            float pw = 0.f;
#pragma unroll
            for (int j = 0; j < C; ++j) pw += scm[(cbase + cc) * C + j] * mall[j];
            z[cc] = lgv[cc] - pw;
        }
    }

    // ---- softmax across the two channel-halves (lane l <-> l+32) ----
    float mx = -1e30f;
#pragma unroll
    for (int cc = 0; cc < NCH0; ++cc) if (cc < nch) mx = fmaxf(mx, z[cc]);
    mx = fmaxf(mx, __shfl_xor(mx, 32));
    float s = 0.f;
#pragma unroll
    for (int cc = 0; cc < NCH0; ++cc)
        if (cc < nch) { z[cc] = __expf(z[cc] - mx); s += z[cc]; }
    s += __shfl_xor(s, 32);
    float inv = 1.f / s;
    float* qo = qout + (size_t)b * C * HW + p;
#pragma unroll
    for (int cc = 0; cc < NCH0; ++cc)
        if (cc < nch) qo[(size_t)(cbase + cc) * HW] = z[cc] * inv;
}

// ---------------------------------------------------------------------------
extern "C" void kernel_launch(void* const* d_in, const int* in_sizes, int n_in,
                              void* d_out, int out_size, void* d_ws, size_t ws_size,
                              hipStream_t stream) {
    const float* logits = (const float*)d_in[0];
    const float* img    = (const float*)d_in[1];
    // d_in[2] = gt_edges (dead code in reference)
    const float* compat = (const float*)d_in[3];
    float* out = (float*)d_out;

    float* qa = (float*)d_ws;                           // Bn*C*HW floats
    float* qb = qa + (size_t)Bn * C * HW;               // Bn*C*HW floats
    unsigned int* wbuf = (unsigned int*)(qb + (size_t)Bn * C * HW);  // Bn*K2*HW u32

    dim3 g(W / TW, H / TH, Bn);                         // 8 x 64 x 2 = 1024 blocks
    crf_iter<<<g, NT, 0, stream>>>(qa, wbuf, logits, img, compat, qb, 1);
    crf_iter<<<g, NT, 0, stream>>>(qb, wbuf, logits, img, compat, qa, 0);
    crf_iter<<<g, NT, 0, stream>>>(qa, wbuf, logits, img, compat, qb, 0);
    crf_iter<<<g, NT, 0, stream>>>(qb, wbuf, logits, img, compat, qa, 0);
    crf_iter<<<g, NT, 0, stream>>>(qa, wbuf, logits, img, compat, out, 0);
}

// Round 10
// 67.443 us; speedup vs baseline: 1.3010x; 1.0903x over previous
//
#include <hip/hip_runtime.h>
#include <hip/hip_fp16.h>

constexpr int Bn = 2, C = 21, H = 256, W = 256, HW = H * W;
constexpr int K = 5, K2 = 25;
constexpr int CQ = 6;                     // channel quads (C padded to 24)

// fused pair kernel geometry
constexpr int TW = 32, TH = 8, NT = 512;  // 256 out px, 2 thr/px
constexpr int EH = TH + 8, EW = TW + 8;   // 16 x 40 extended (q_t)
constexpr int MH = TH + 4, MW = TW + 4;   // 12 x 36 mid (q_{t+1})
constexpr int NEC = EH * EW;              // 640
constexpr int NMC = MH * MW;              // 432

// final single-iter kernel geometry (proven R9)
constexpr int TH3 = 4, NT3 = 256;
constexpr int LH3 = TH3 + 4, LW3 = TW + 4;  // 8 x 36
constexpr int NC3 = LH3 * LW3;              // 288

union H2U { __half2 h; unsigned int u; };

// ---------------------------------------------------------------------------
// Packed bilateral weights from an LDS img tile (center identity folded in:
// spatial gaussian sigma=0.1 is a delta => +1 at k=12). ey/ex = tile coords.
// ---------------------------------------------------------------------------
__device__ __forceinline__ void compute_wk(const float4* simg, int ldw,
                                           int ey, int ex, unsigned int* wk) {
    float4 ctr = simg[ey * ldw + ex];
    float S = 0.f;
#pragma unroll
    for (int k = 0; k < K2; ++k) {
        int dy = k / K - 2, dx = k % K - 2;
        S += __expf(-(float)(dy * dy + dx * dx) * 0.02f);   // sigma_s = 5
    }
    float invS = 1.f / S;
#pragma unroll
    for (int k = 0; k < K2; ++k) {
        int dy = k / K - 2, dx = k % K - 2;
        float4 nb = simg[(ey + dy) * ldw + (ex + dx)];
        float d0 = nb.x - ctr.x, d1 = nb.y - ctr.y, d2 = nb.z - ctr.z;
        float sk = __expf(-(float)(dy * dy + dx * dx) * 0.02f);
        float wv = sk * invS * __expf(-(d0 * d0 + d1 * d1 + d2 * d2) * 50.f);
        if (k == 12) wv += 1.0f;          // fold identity spatial conv
        H2U cv; cv.h = __float2half2_rn(wv);
        wk[k] = cv.u;
    }
}

// ---------------------------------------------------------------------------
// Fused pair: two mean-field iterations per launch.
// INIT=1: q_t = softmax(logits) computed on the extended tile (no q read).
// iter-a: 1 thread/cell over the 12x36 mid region, all channels in-thread,
//         result kept in LDS (bufB, fp16 quads).
// iter-b: 2 thr/px over the 8x32 interior (proven R9 pattern), writes global.
// compat == -I fast path (runtime-verified, block-uniform); general matvec
// kept correct on both phases.
// ---------------------------------------------------------------------------
template <int INIT>
__global__ __launch_bounds__(NT, 4) void crf_pair(
        const float* __restrict__ qin, const float* __restrict__ logits,
        const float* __restrict__ img, const float* __restrict__ compat,
        float* __restrict__ qout) {
    __shared__ __align__(16) __half2 bufA[CQ][EH][EW][2];  // 30720 B (q_t)
    __shared__ __align__(16) __half2 bufB[CQ][MH][MW][2];  // 20736 B (q_{t+1})
    __shared__ float4 simg[NEC];                           // 10240 B
    __shared__ float scm[C * C];                           // 1764 B

    const int b = blockIdx.z;
    const int x0 = blockIdx.x * TW, y0 = blockIdx.y * TH;
    const int tid = threadIdx.x;

    // ---- stage compat (+ -I check) ----
    int ok = 1;
    for (int i = tid; i < C * C; i += NT) {
        float v = compat[i];
        scm[i] = v;
        ok &= (v == ((i / C == i % C) ? -1.0f : 0.0f));
    }

    const float* im = img + (size_t)b * 3 * HW;

    // ---- stage extended tile: img and q_t ----
    if (INIT) {
        for (int cell = tid; cell < NEC; cell += NT) {
            int ey = cell / EW, ex = cell % EW;
            int gy = y0 + ey - 4, gx = x0 + ex - 4;
            float4 iv = make_float4(0.f, 0.f, 0.f, 0.f);
            float vals[24];
            if ((unsigned)gy < H && (unsigned)gx < W) {
                int np = gy * W + gx;
                iv.x = im[np]; iv.y = im[HW + np]; iv.z = im[2 * HW + np];
                const float* lg = logits + (size_t)b * C * HW + np;
                float zz[C], mx = -1e30f;
#pragma unroll
                for (int c = 0; c < C; ++c) {
                    zz[c] = lg[(size_t)c * HW];
                    mx = fmaxf(mx, zz[c]);
                }
                float s = 0.f;
#pragma unroll
                for (int c = 0; c < C; ++c) { zz[c] = __expf(zz[c] - mx); s += zz[c]; }
                float inv = 1.f / s;
#pragma unroll
                for (int c = 0; c < 24; ++c) vals[c] = (c < C) ? zz[c] * inv : 0.f;
            } else {
#pragma unroll
                for (int c = 0; c < 24; ++c) vals[c] = 0.f;
            }
            simg[cell] = iv;
#pragma unroll
            for (int g = 0; g < CQ; ++g) {
                bufA[g][ey][ex][0] = __floats2half2_rn(vals[4 * g + 0], vals[4 * g + 1]);
                bufA[g][ey][ex][1] = __floats2half2_rn(vals[4 * g + 2], vals[4 * g + 3]);
            }
        }
    } else {
        for (int cell = tid; cell < NEC; cell += NT) {
            int ey = cell / EW, ex = cell % EW;
            int gy = y0 + ey - 4, gx = x0 + ex - 4;
            float4 iv = make_float4(0.f, 0.f, 0.f, 0.f);
            if ((unsigned)gy < H && (unsigned)gx < W) {
                int np = gy * W + gx;
                iv.x = im[np]; iv.y = im[HW + np]; iv.z = im[2 * HW + np];
            }
            simg[cell] = iv;
        }
        const float* qsrc = qin + (size_t)b * C * HW;
        for (int i = tid; i < CQ * NEC; i += NT) {
            int g = i / NEC, cell = i % NEC;
            int ey = cell / EW, ex = cell % EW;
            int gy = y0 + ey - 4, gx = x0 + ex - 4;
            float4 v = make_float4(0.f, 0.f, 0.f, 0.f);
            if ((unsigned)gy < H && (unsigned)gx < W) {
                const float* qp = qsrc + gy * W + gx;
                int c0 = 4 * g;
                v.x = qp[(size_t)c0 * HW];
                v.y = (c0 + 1 < C) ? qp[(size_t)(c0 + 1) * HW] : 0.f;
                v.z = (c0 + 2 < C) ? qp[(size_t)(c0 + 2) * HW] : 0.f;
                v.w = (c0 + 3 < C) ? qp[(size_t)(c0 + 3) * HW] : 0.f;
            }
            bufA[g][ey][ex][0] = __floats2half2_rn(v.x, v.y);
            bufA[g][ey][ex][1] = __floats2half2_rn(v.z, v.w);
        }
    }
    const int fast = __syncthreads_and(ok);

    // ======================= iter-a: mid region =============================
    if (tid < NMC) {
        const int my = tid / MW, mx = tid % MW;
        const int gy = y0 + my - 2, gx = x0 + mx - 2;
        if ((unsigned)gy < H && (unsigned)gx < W) {
            const float* lgp = logits + (size_t)b * C * HW + gy * W + gx;
            float lg[C];
#pragma unroll
            for (int c = 0; c < C; ++c) lg[c] = lgp[(size_t)c * HW];

            unsigned int wk[K2];
            compute_wk(simg, EW, my + 2, mx + 2, wk);

            const __half2 zero2 = __float2half2_rn(0.f);
            __half2 aA[CQ][2], aB[CQ][2];
#pragma unroll
            for (int g = 0; g < CQ; ++g) {
                aA[g][0] = zero2; aA[g][1] = zero2;
                aB[g][0] = zero2; aB[g][1] = zero2;
            }
#pragma unroll
            for (int k = 0; k < K2; ++k) {
                const int ly = my + k / K, lx = mx + k % K;
                H2U wv; wv.u = wk[k];
#pragma unroll
                for (int g = 0; g < CQ; ++g) {
                    const uint2 raw = *reinterpret_cast<const uint2*>(&bufA[g][ly][lx][0]);
                    H2U q01, q23; q01.u = raw.x; q23.u = raw.y;
                    if (k < 13) {
                        aA[g][0] = __hfma2(wv.h, q01.h, aA[g][0]);
                        aA[g][1] = __hfma2(wv.h, q23.h, aA[g][1]);
                    } else {
                        aB[g][0] = __hfma2(wv.h, q01.h, aB[g][0]);
                        aB[g][1] = __hfma2(wv.h, q23.h, aB[g][1]);
                    }
                }
            }
            float m[24];
#pragma unroll
            for (int g = 0; g < CQ; ++g) {
                float2 lA = __half22float2(aA[g][0]), lB = __half22float2(aB[g][0]);
                float2 hA = __half22float2(aA[g][1]), hB = __half22float2(aB[g][1]);
                m[4 * g + 0] = lA.x + lB.x;
                m[4 * g + 1] = lA.y + lB.y;
                m[4 * g + 2] = hA.x + hB.x;
                m[4 * g + 3] = hA.y + hB.y;
            }
            float z[C], mx2 = -1e30f;
            if (fast) {
#pragma unroll
                for (int c = 0; c < C; ++c) { z[c] = lg[c] + m[c]; mx2 = fmaxf(mx2, z[c]); }
            } else {
#pragma unroll
                for (int c = 0; c < C; ++c) {
                    float pw = 0.f;
#pragma unroll
                    for (int j = 0; j < C; ++j) pw += scm[c * C + j] * m[j];
                    z[c] = lg[c] - pw; mx2 = fmaxf(mx2, z[c]);
                }
            }
            float s = 0.f;
#pragma unroll
            for (int c = 0; c < C; ++c) { z[c] = __expf(z[c] - mx2); s += z[c]; }
            float inv = 1.f / s;
            float vals[24];
#pragma unroll
            for (int c = 0; c < 24; ++c) vals[c] = (c < C) ? z[c] * inv : 0.f;
#pragma unroll
            for (int g = 0; g < CQ; ++g) {
                bufB[g][my][mx][0] = __floats2half2_rn(vals[4 * g + 0], vals[4 * g + 1]);
                bufB[g][my][mx][1] = __floats2half2_rn(vals[4 * g + 2], vals[4 * g + 3]);
            }
        } else {
            const __half2 zero2 = __float2half2_rn(0.f);
#pragma unroll
            for (int g = 0; g < CQ; ++g) {
                bufB[g][my][mx][0] = zero2;
                bufB[g][my][mx][1] = zero2;
            }
        }
    }
    __syncthreads();

    // ======================= iter-b: interior, 2 thr/px =====================
    {
        const int px = tid & 31;
        const int half = (tid >> 5) & 1;
        const int py = tid >> 6;                 // 0..7
        const int p = (y0 + py) * W + (x0 + px);
        const int pi = py * TW + px;             // 0..255
        const int qoff = half * 3;
        const int cbase = half ? 12 : 0;
        const int nch = half ? 9 : 12;

        unsigned int wk2[K2];
        compute_wk(simg, EW, py + 4, px + 4, wk2);

        const float* lgp = logits + (size_t)b * C * HW + p;
        float lgv[12];
#pragma unroll
        for (int cc = 0; cc < 12; ++cc)
            lgv[cc] = (cc < nch) ? lgp[(size_t)(cbase + cc) * HW] : 0.f;

        const __half2 zero2 = __float2half2_rn(0.f);
        __half2 a01A[3], a23A[3], a01B[3], a23B[3];
#pragma unroll
        for (int g = 0; g < 3; ++g) { a01A[g] = zero2; a23A[g] = zero2;
                                      a01B[g] = zero2; a23B[g] = zero2; }
#pragma unroll
        for (int k = 0; k < K2; ++k) {
            const int ly = py + k / K, lx = px + k % K;
            H2U wv; wv.u = wk2[k];
#pragma unroll
            for (int g = 0; g < 3; ++g) {
                const uint2 raw = *reinterpret_cast<const uint2*>(&bufB[qoff + g][ly][lx][0]);
                H2U q01, q23; q01.u = raw.x; q23.u = raw.y;
                if (k < 13) {
                    a01A[g] = __hfma2(wv.h, q01.h, a01A[g]);
                    a23A[g] = __hfma2(wv.h, q23.h, a23A[g]);
                } else {
                    a01B[g] = __hfma2(wv.h, q01.h, a01B[g]);
                    a23B[g] = __hfma2(wv.h, q23.h, a23B[g]);
                }
            }
        }
        float mreg[12];
#pragma unroll
        for (int g = 0; g < 3; ++g) {
            float2 lA = __half22float2(a01A[g]), lB = __half22float2(a01B[g]);
            float2 hA = __half22float2(a23A[g]), hB = __half22float2(a23B[g]);
            mreg[4 * g + 0] = lA.x + lB.x;
            mreg[4 * g + 1] = lA.y + lB.y;
            mreg[4 * g + 2] = hA.x + hB.x;
            mreg[4 * g + 3] = hA.y + hB.y;
        }

        float z[12];
        if (fast) {
#pragma unroll
            for (int cc = 0; cc < 12; ++cc) z[cc] = lgv[cc] + mreg[cc];
        } else {                            // general matvec via bufA reuse
            __syncthreads();
            float* smf = (float*)&bufA[0][0][0][0];   // 256*21*4 B < 30720 B
#pragma unroll
            for (int cc = 0; cc < 12; ++cc)
                if (cc < nch) smf[pi * C + cbase + cc] = mreg[cc];
            __syncthreads();
            float mall[C];
#pragma unroll
            for (int j = 0; j < C; ++j) mall[j] = smf[pi * C + j];
#pragma unroll
            for (int cc = 0; cc < 12; ++cc) {
                float pw = 0.f;
#pragma unroll
                for (int j = 0; j < C; ++j) pw += scm[(cbase + cc) * C + j] * mall[j];
                z[cc] = lgv[cc] - pw;
            }
        }

        float mx = -1e30f;
#pragma unroll
        for (int cc = 0; cc < 12; ++cc) if (cc < nch) mx = fmaxf(mx, z[cc]);
        mx = fmaxf(mx, __shfl_xor(mx, 32));
        float s = 0.f;
#pragma unroll
        for (int cc = 0; cc < 12; ++cc)
            if (cc < nch) { z[cc] = __expf(z[cc] - mx); s += z[cc]; }
        s += __shfl_xor(s, 32);
        float inv = 1.f / s;
        float* qo = qout + (size_t)b * C * HW + p;
#pragma unroll
        for (int cc = 0; cc < 12; ++cc)
            if (cc < nch) qo[(size_t)(cbase + cc) * HW] = z[cc] * inv;
    }
}

// ---------------------------------------------------------------------------
// Final single iteration (proven R9 structure; wk recomputed from img tile).
// ---------------------------------------------------------------------------
__global__ __launch_bounds__(NT3, 4) void crf_final(
        const float* __restrict__ qin, const float* __restrict__ logits,
        const float* __restrict__ img, const float* __restrict__ compat,
        float* __restrict__ out) {
    __shared__ __align__(16) __half2 sqh[CQ][LH3][LW3][2];  // 13824 B
    __shared__ float4 simg[NC3];                            // 4608 B
    __shared__ float scm[C * C];                            // 1764 B

    const int b = blockIdx.z;
    const int x0 = blockIdx.x * TW, y0 = blockIdx.y * TH3;
    const int tid = threadIdx.x;
    const int px = tid & 31;
    const int half = (tid >> 5) & 1;
    const int py = tid >> 6;             // 0..3
    const int p = (y0 + py) * W + (x0 + px);
    const int pi = py * TW + px;         // 0..127
    const int qoff = half * 3;
    const int cbase = half ? 12 : 0;
    const int nch = half ? 9 : 12;

    int ok = 1;
    for (int i = tid; i < C * C; i += NT3) {
        float v = compat[i];
        scm[i] = v;
        ok &= (v == ((i / C == i % C) ? -1.0f : 0.0f));
    }
    const float* im = img + (size_t)b * 3 * HW;
    for (int cell = tid; cell < NC3; cell += NT3) {
        int ly = cell / LW3, lx = cell % LW3;
        int gy = y0 + ly - 2, gx = x0 + lx - 2;
        float4 iv = make_float4(0.f, 0.f, 0.f, 0.f);
        if ((unsigned)gy < H && (unsigned)gx < W) {
            int np = gy * W + gx;
            iv.x = im[np]; iv.y = im[HW + np]; iv.z = im[2 * HW + np];
        }
        simg[cell] = iv;
    }
    const float* qsrc = qin + (size_t)b * C * HW;
    for (int i = tid; i < CQ * NC3; i += NT3) {
        int g = i / NC3, r = i % NC3;
        int ly = r / LW3, lx = r % LW3;
        int gy = y0 + ly - 2, gx = x0 + lx - 2;
        float4 v = make_float4(0.f, 0.f, 0.f, 0.f);
        if ((unsigned)gy < H && (unsigned)gx < W) {
            const float* qp = qsrc + gy * W + gx;
            int c0 = 4 * g;
            v.x = qp[(size_t)c0 * HW];
            v.y = (c0 + 1 < C) ? qp[(size_t)(c0 + 1) * HW] : 0.f;
            v.z = (c0 + 2 < C) ? qp[(size_t)(c0 + 2) * HW] : 0.f;
            v.w = (c0 + 3 < C) ? qp[(size_t)(c0 + 3) * HW] : 0.f;
        }
        sqh[g][ly][lx][0] = __floats2half2_rn(v.x, v.y);
        sqh[g][ly][lx][1] = __floats2half2_rn(v.z, v.w);
    }
    const int fast = __syncthreads_and(ok);

    unsigned int wk2[K2];
    compute_wk(simg, LW3, py + 2, px + 2, wk2);

    const float* lgp = logits + (size_t)b * C * HW + p;
    float lgv[12];
#pragma unroll
    for (int cc = 0; cc < 12; ++cc)
        lgv[cc] = (cc < nch) ? lgp[(size_t)(cbase + cc) * HW] : 0.f;

    const __half2 zero2 = __float2half2_rn(0.f);
    __half2 a01A[3], a23A[3], a01B[3], a23B[3];
#pragma unroll
    for (int g = 0; g < 3; ++g) { a01A[g] = zero2; a23A[g] = zero2;
                                  a01B[g] = zero2; a23B[g] = zero2; }
#pragma unroll
    for (int k = 0; k < K2; ++k) {
        const int ly = py + k / K, lx = px + k % K;
        H2U wv; wv.u = wk2[k];
#pragma unroll
        for (int g = 0; g < 3; ++g) {
            const uint2 raw = *reinterpret_cast<const uint2*>(&sqh[qoff + g][ly][lx][0]);
            H2U q01, q23; q01.u = raw.x; q23.u = raw.y;
            if (k < 13) {
                a01A[g] = __hfma2(wv.h, q01.h, a01A[g]);
                a23A[g] = __hfma2(wv.h, q23.h, a23A[g]);
            } else {
                a01B[g] = __hfma2(wv.h, q01.h, a01B[g]);
                a23B[g] = __hfma2(wv.h, q23.h, a23B[g]);
            }
        }
    }
    float mreg[12];
#pragma unroll
    for (int g = 0; g < 3; ++g) {
        float2 lA = __half22float2(a01A[g]), lB = __half22float2(a01B[g]);
        float2 hA = __half22float2(a23A[g]), hB = __half22float2(a23B[g]);
        mreg[4 * g + 0] = lA.x + lB.x;
        mreg[4 * g + 1] = lA.y + lB.y;
        mreg[4 * g + 2] = hA.x + hB.x;
        mreg[4 * g + 3] = hA.y + hB.y;
    }

    float z[12];
    if (fast) {
#pragma unroll
        for (int cc = 0; cc < 12; ++cc) z[cc] = lgv[cc] + mreg[cc];
    } else {
        __syncthreads();
        float* smf = (float*)&sqh[0][0][0][0];   // 128*21*4 B < 13824 B
#pragma unroll
        for (int cc = 0; cc < 12; ++cc)
            if (cc < nch) smf[pi * C + cbase + cc] = mreg[cc];
        __syncthreads();
        float mall[C];
#pragma unroll
        for (int j = 0; j < C; ++j) mall[j] = smf[pi * C + j];
#pragma unroll
        for (int cc = 0; cc < 12; ++cc) {
            float pw = 0.f;
#pragma unroll
            for (int j = 0; j < C; ++j) pw += scm[(cbase + cc) * C + j] * mall[j];
            z[cc] = lgv[cc] - pw;
        }
    }

    float mx = -1e30f;
#pragma unroll
    for (int cc = 0; cc < 12; ++cc) if (cc < nch) mx = fmaxf(mx, z[cc]);
    mx = fmaxf(mx, __shfl_xor(mx, 32));
    float s = 0.f;
#pragma unroll
    for (int cc = 0; cc < 12; ++cc)
        if (cc < nch) { z[cc] = __expf(z[cc] - mx); s += z[cc]; }
    s += __shfl_xor(s, 32);
    float inv = 1.f / s;
    float* qo = out + (size_t)b * C * HW + p;
#pragma unroll
    for (int cc = 0; cc < 12; ++cc)
        if (cc < nch) qo[(size_t)(cbase + cc) * HW] = z[cc] * inv;
}

// ---------------------------------------------------------------------------
extern "C" void kernel_launch(void* const* d_in, const int* in_sizes, int n_in,
                              void* d_out, int out_size, void* d_ws, size_t ws_size,
                              hipStream_t stream) {
    const float* logits = (const float*)d_in[0];
    const float* img    = (const float*)d_in[1];
    // d_in[2] = gt_edges (dead code in reference)
    const float* compat = (const float*)d_in[3];
    float* out = (float*)d_out;

    float* qa = (float*)d_ws;                       // Bn*C*HW floats (q2)
    float* qb = qa + (size_t)Bn * C * HW;           // Bn*C*HW floats (q4)

    dim3 gp(W / TW, H / TH, Bn);                    // 8 x 32 x 2 = 512 blocks
    crf_pair<1><<<gp, NT, 0, stream>>>(qa, logits, img, compat, qa);   // q0 -> q2
    crf_pair<0><<<gp, NT, 0, stream>>>(qa, logits, img, compat, qb);   // q2 -> q4
    dim3 gf(W / TW, H / TH3, Bn);                   // 8 x 64 x 2 = 1024 blocks
    crf_final<<<gf, NT3, 0, stream>>>(qb, logits, img, compat, out);   // q4 -> out
}

// Round 11
// 58.917 us; speedup vs baseline: 1.4893x; 1.1447x over previous
//
#include <hip/hip_runtime.h>
#include <hip/hip_fp16.h>

constexpr int Bn = 2, C = 21, H = 256, W = 256, HW = H * W;
constexpr int K2 = 25;
constexpr int CQ = 6;                       // channel quads (C padded to 24)
constexpr int TW = 32, TH = 16, NT = 1024;  // output tile / block size
constexpr int HALO = 10;                    // 5 iterations x 2-halo
constexpr int EH = TH + 2 * HALO;           // 36
constexpr int EW = TW + 2 * HALO;           // 52
constexpr int NEC = EH * EW;                // 1872

// Normalized spatial gaussian (sigma=5): exp(-(dy^2+dx^2)/50)/S, S=23.1036923.
// Baked as literals (f64-accurate; ~1e-7 vs reference's f32 compute).
__device__ constexpr float SKN[K2] = {
    0.03688346f, 0.03916421f, 0.03995538f, 0.03916421f, 0.03688346f,
    0.03916421f, 0.04158598f, 0.04242608f, 0.04158598f, 0.03916421f,
    0.03995538f, 0.04242608f, 0.04328314f, 0.04242608f, 0.03995538f,
    0.03916421f, 0.04158598f, 0.04242608f, 0.04158598f, 0.03916421f,
    0.03688346f, 0.03916421f, 0.03995538f, 0.03916421f, 0.03688346f};

union H2U { __half2 h; unsigned int u; };

// ---------------------------------------------------------------------------
// One mean-field iteration over the shrinking region (margin = MARGIN cells
// from the extended-tile edge). Reads bufQ (old q), computes new q into
// registers, barrier, writes back in place, barrier. FINAL writes f32 to out
// directly (nothing reads bufQ afterwards -> no barriers needed).
// ---------------------------------------------------------------------------
template <int MARGIN, bool FINAL>
__device__ __forceinline__ void mf_iter(
        int tid, int b, int y0, int x0, int fast,
        const float* __restrict__ lgb, const float* __restrict__ scm,
        __half2 (*bufQ)[EH][EW][2], const float4* simg,
        float* __restrict__ outp) {
    constexpr int HT_ = EH - 2 * MARGIN, WT_ = EW - 2 * MARGIN;
    constexpr int NCEL = HT_ * WT_;
    constexpr int NS = (NCEL + NT - 1) / NT;
    unsigned int nq[NS][12];
    bool valid[NS];
#pragma unroll
    for (int s = 0; s < NS; ++s) {
        valid[s] = false;
        const int cell = tid + s * NT;
        if (cell < NCEL) {
            const int ry = cell / WT_, rx = cell % WT_;      // WT_ constexpr
            const int ey = MARGIN + ry, ex = MARGIN + rx;
            const int gy = y0 + ey - HALO, gx = x0 + ex - HALO;
            if ((unsigned)gy < H && (unsigned)gx < W) {
                valid[s] = true;
                // ---- logits (issued early, in flight under wk exp chain) --
                const float* lgp = lgb + gy * W + gx;
                float lg[C];
#pragma unroll
                for (int c = 0; c < C; ++c) lg[c] = lgp[(size_t)c * HW];
                // ---- bilateral weights from LDS img tile ----
                const float4 ctr = simg[ey * EW + ex];
                unsigned int wk[K2];
#pragma unroll
                for (int k = 0; k < K2; ++k) {
                    const int dy = k / 5 - 2, dx = k % 5 - 2;
                    const float4 nb = simg[(ey + dy) * EW + (ex + dx)];
                    const float d0 = nb.x - ctr.x, d1 = nb.y - ctr.y,
                                d2 = nb.z - ctr.z;
                    float wv = SKN[k] *
                        __expf(-50.f * (d0 * d0 + d1 * d1 + d2 * d2));
                    if (k == 12) wv += 1.0f;   // identity (delta) spatial conv
                    H2U cv; cv.h = __float2half2_rn(wv);
                    wk[k] = cv.u;
                }
                // ---- 25 taps x 6 quads, fp16 A/B partial accumulators ----
                const __half2 zero2 = __float2half2_rn(0.f);
                __half2 aA[CQ][2], aB[CQ][2];
#pragma unroll
                for (int g = 0; g < CQ; ++g) {
                    aA[g][0] = zero2; aA[g][1] = zero2;
                    aB[g][0] = zero2; aB[g][1] = zero2;
                }
#pragma unroll
                for (int k = 0; k < K2; ++k) {
                    const int ly = ey + k / 5 - 2, lx = ex + k % 5 - 2;
                    H2U wv; wv.u = wk[k];
#pragma unroll
                    for (int g = 0; g < CQ; ++g) {
                        const uint2 raw =
                            *reinterpret_cast<const uint2*>(&bufQ[g][ly][lx][0]);
                        H2U q01, q23; q01.u = raw.x; q23.u = raw.y;
                        if (k < 13) {
                            aA[g][0] = __hfma2(wv.h, q01.h, aA[g][0]);
                            aA[g][1] = __hfma2(wv.h, q23.h, aA[g][1]);
                        } else {
                            aB[g][0] = __hfma2(wv.h, q01.h, aB[g][0]);
                            aB[g][1] = __hfma2(wv.h, q23.h, aB[g][1]);
                        }
                    }
                }
                float m[24];
#pragma unroll
                for (int g = 0; g < CQ; ++g) {
                    const float2 lA = __half22float2(aA[g][0]);
                    const float2 lB = __half22float2(aB[g][0]);
                    const float2 hA = __half22float2(aA[g][1]);
                    const float2 hB = __half22float2(aB[g][1]);
                    m[4 * g + 0] = lA.x + lB.x;
                    m[4 * g + 1] = lA.y + lB.y;
                    m[4 * g + 2] = hA.x + hB.x;
                    m[4 * g + 3] = hA.y + hB.y;
                }
                // ---- compatibility + softmax (all thread-local) ----
                float z[C], mx = -1e30f;
                if (fast) {                  // compat == -I: z = logits + m
#pragma unroll
                    for (int c = 0; c < C; ++c) {
                        z[c] = lg[c] + m[c]; mx = fmaxf(mx, z[c]);
                    }
                } else {                     // general matvec, local
#pragma unroll
                    for (int c = 0; c < C; ++c) {
                        float pw = 0.f;
#pragma unroll
                        for (int j = 0; j < C; ++j) pw += scm[c * C + j] * m[j];
                        z[c] = lg[c] - pw; mx = fmaxf(mx, z[c]);
                    }
                }
                float ssum = 0.f;
#pragma unroll
                for (int c = 0; c < C; ++c) {
                    z[c] = __expf(z[c] - mx); ssum += z[c];
                }
                const float inv = 1.f / ssum;
                if (FINAL) {
                    float* qo = outp + (size_t)b * C * HW + gy * W + gx;
#pragma unroll
                    for (int c = 0; c < C; ++c) qo[(size_t)c * HW] = z[c] * inv;
                } else {
                    float vals[24];
#pragma unroll
                    for (int c = 0; c < 24; ++c)
                        vals[c] = (c < C) ? z[c] * inv : 0.f;
#pragma unroll
                    for (int g = 0; g < CQ; ++g) {
                        H2U p0; p0.h = __floats2half2_rn(vals[4 * g + 0], vals[4 * g + 1]);
                        H2U p1; p1.h = __floats2half2_rn(vals[4 * g + 2], vals[4 * g + 3]);
                        nq[s][2 * g + 0] = p0.u;
                        nq[s][2 * g + 1] = p1.u;
                    }
                }
            }
        }
    }
    if (!FINAL) {
        __syncthreads();                     // all reads of old q done
#pragma unroll
        for (int s = 0; s < NS; ++s) {
            if (valid[s]) {
                const int cell = tid + s * NT;
                const int ry = cell / WT_, rx = cell % WT_;
                const int ey = MARGIN + ry, ex = MARGIN + rx;
#pragma unroll
                for (int g = 0; g < CQ; ++g)
                    *reinterpret_cast<uint2*>(&bufQ[g][ey][ex][0]) =
                        make_uint2(nq[s][2 * g], nq[s][2 * g + 1]);
            }
        }
        __syncthreads();                     // new q visible
    }
}

// ---------------------------------------------------------------------------
// Mega-fused CRF: q0 = softmax(logits) staged on a 36x52 extended tile, then
// all 5 mean-field iterations in-LDS with shrinking regions. One dispatch,
// 256 blocks (1/CU) x 1024 threads. LDS = 121.6 KB.
// ---------------------------------------------------------------------------
__global__ __launch_bounds__(NT, 4) void crf_mega(
        const float* __restrict__ logits, const float* __restrict__ img,
        const float* __restrict__ compat, float* __restrict__ out) {
    __shared__ __align__(16) __half2 bufQ[CQ][EH][EW][2];  // 89856 B
    __shared__ __align__(16) float4 simg[NEC];             // 29952 B
    __shared__ float scm[C * C];                           // 1764 B

    const int b = blockIdx.z;
    const int x0 = blockIdx.x * TW, y0 = blockIdx.y * TH;
    const int tid = threadIdx.x;

    // ---- compat stage (+ -I check) ----
    int ok = 1;
    for (int i = tid; i < C * C; i += NT) {
        const float v = compat[i];
        scm[i] = v;
        ok &= (v == ((i / C == i % C) ? -1.0f : 0.0f));
    }

    const float* im  = img + (size_t)b * 3 * HW;
    const float* lgb = logits + (size_t)b * C * HW;

    // ---- stage img (f32) and q0 = softmax(logits) (fp16 quads) ----
    for (int cell = tid; cell < NEC; cell += NT) {
        const int ey = cell / EW, ex = cell % EW;
        const int gy = y0 + ey - HALO, gx = x0 + ex - HALO;
        float4 iv = make_float4(0.f, 0.f, 0.f, 0.f);
        float vals[24];
        if ((unsigned)gy < H && (unsigned)gx < W) {
            const int np = gy * W + gx;
            iv.x = im[np]; iv.y = im[HW + np]; iv.z = im[2 * HW + np];
            const float* lg = lgb + np;
            float zz[C], mx = -1e30f;
#pragma unroll
            for (int c = 0; c < C; ++c) {
                zz[c] = lg[(size_t)c * HW]; mx = fmaxf(mx, zz[c]);
            }
            float ssum = 0.f;
#pragma unroll
            for (int c = 0; c < C; ++c) { zz[c] = __expf(zz[c] - mx); ssum += zz[c]; }
            const float inv = 1.f / ssum;
#pragma unroll
            for (int c = 0; c < 24; ++c) vals[c] = (c < C) ? zz[c] * inv : 0.f;
        } else {
#pragma unroll
            for (int c = 0; c < 24; ++c) vals[c] = 0.f;
        }
        simg[cell] = iv;
#pragma unroll
        for (int g = 0; g < CQ; ++g) {
            bufQ[g][ey][ex][0] = __floats2half2_rn(vals[4 * g + 0], vals[4 * g + 1]);
            bufQ[g][ey][ex][1] = __floats2half2_rn(vals[4 * g + 2], vals[4 * g + 3]);
        }
    }
    const int fast = __syncthreads_and(ok);

    // ---- 5 fused iterations, shrinking regions (margins 2,4,6,8,10) ----
    mf_iter< 2, false>(tid, b, y0, x0, fast, lgb, scm, bufQ, simg, out);
    mf_iter< 4, false>(tid, b, y0, x0, fast, lgb, scm, bufQ, simg, out);
    mf_iter< 6, false>(tid, b, y0, x0, fast, lgb, scm, bufQ, simg, out);
    mf_iter< 8, false>(tid, b, y0, x0, fast, lgb, scm, bufQ, simg, out);
    mf_iter<10, true >(tid, b, y0, x0, fast, lgb, scm, bufQ, simg, out);
}

// ---------------------------------------------------------------------------
extern "C" void kernel_launch(void* const* d_in, const int* in_sizes, int n_in,
                              void* d_out, int out_size, void* d_ws, size_t ws_size,
                              hipStream_t stream) {
    const float* logits = (const float*)d_in[0];
    const float* img    = (const float*)d_in[1];
    // d_in[2] = gt_edges (dead code in reference)
    const float* compat = (const float*)d_in[3];
    float* out = (float*)d_out;

    dim3 g(W / TW, H / TH, Bn);      // 8 x 16 x 2 = 256 blocks = 1 per CU
    crf_mega<<<g, NT, 0, stream>>>(logits, img, compat, out);
}